// Round 6
// baseline (276.032 us; speedup 1.0000x reference)
//
#include <hip/hip_runtime.h>

// SpinorBilinears v5: persistent grid-stride blocks (fill-kernel shape).
// 2048 blocks x 256 threads, each handles 4 chunks of 64 tokens.
// Inner math identical to verified v4: waves 0-1 compute T rows (wave-uniform
// gamma -> s_loads), all 4 waves stream K1/K2 with nt coalesced stores.
// psi for chunk i+1 is prefetched before chunk i's store burst.
// Tokens = B*N = 524288, S=4, C=8. Outputs f32 concat: K0 | K1 | K2.

#define TPB 256
#define TOK 64        // tokens per chunk
#define STRIDE 68     // 64 + 4 pad: bank-balanced LDS (verified r0/v4)
#define GRID 2048     // 8 blocks/CU target; persistent grid-stride

typedef float f32x4 __attribute__((ext_vector_type(4)));

__device__ __forceinline__ float dot4(float4 a, float4 b) {
    return a.x * b.x + a.y * b.y + a.z * b.z + a.w * b.w;
}

__global__ __launch_bounds__(TPB) void spinor_bilinears_v5(
    const float* __restrict__ psi,
    const float* __restrict__ gamma,
    float* __restrict__ out,
    long long n_tokens) {
    __shared__ float ldsT[TOK * STRIDE];   // 17408 B -> 8 blocks/CU fits LDS

    const int tid = threadIdx.x;
    const int wave = tid >> 6;
    const int lane = tid & 63;
    const long long nchunks = n_tokens / TOK;   // 8192

    const float4* __restrict__ psi4 = (const float4*)psi;
    const float4* __restrict__ g4 = (const float4*)gamma;  // g4[c*4+i]
    f32x4* K1 = (f32x4*)(out + n_tokens);
    f32x4* K2 = (f32x4*)(out + n_tokens + n_tokens * 64);

    float4 p = make_float4(0.f, 0.f, 0.f, 0.f);
    if (wave < 2) {
        p = psi4[(long long)blockIdx.x * TOK + lane];   // chunk 0 psi
    }

    for (long long chunk = blockIdx.x; chunk < nchunks; chunk += GRID) {
        // ---- Phase 1: waves 0,1 compute T rows for 64 tokens ----
        if (wave < 2) {
            const long long t = chunk * TOK + lane;
            if (wave == 0) {
                __builtin_nontemporal_store(dot4(p, p), &out[t]);  // K0
            }
            // v[d] = Gd psi (all gamma addresses wave-uniform -> SGPRs)
            float4 v[8];
#pragma unroll
            for (int d = 0; d < 8; ++d) {
                const float4 g0 = g4[d * 4 + 0];
                const float4 g1 = g4[d * 4 + 1];
                const float4 g2 = g4[d * 4 + 2];
                const float4 g3 = g4[d * 4 + 3];
                float4 vd;
                vd.x = dot4(g0, p);
                vd.y = dot4(g1, p);
                vd.z = dot4(g2, p);
                vd.w = dot4(g3, p);
                v[d] = vd;
            }
            // u[c] = psi^T Gc for this wave's 4 rows; T rows -> LDS
            float* trow = &ldsT[lane * STRIDE];
#pragma unroll
            for (int i = 0; i < 4; ++i) {
                const int c = wave * 4 + i;    // wave-uniform
                const float4 g0 = g4[c * 4 + 0];
                const float4 g1 = g4[c * 4 + 1];
                const float4 g2 = g4[c * 4 + 2];
                const float4 g3 = g4[c * 4 + 3];
                float4 u;
                u.x = p.x * g0.x + p.y * g1.x + p.z * g2.x + p.w * g3.x;
                u.y = p.x * g0.y + p.y * g1.y + p.z * g2.y + p.w * g3.y;
                u.z = p.x * g0.z + p.y * g1.z + p.z * g2.z + p.w * g3.z;
                u.w = p.x * g0.w + p.y * g1.w + p.z * g2.w + p.w * g3.w;
                f32x4 q0, q1;
                q0[0] = dot4(u, v[0]); q0[1] = dot4(u, v[1]);
                q0[2] = dot4(u, v[2]); q0[3] = dot4(u, v[3]);
                q1[0] = dot4(u, v[4]); q1[1] = dot4(u, v[5]);
                q1[2] = dot4(u, v[6]); q1[3] = dot4(u, v[7]);
                *(f32x4*)(trow + c * 8 + 0) = q0;
                *(f32x4*)(trow + c * 8 + 4) = q1;
            }
        }
        __syncthreads();

        // Prefetch next chunk's psi; latency hides under the store burst.
        if (wave < 2 && chunk + GRID < nchunks) {
            p = psi4[(chunk + GRID) * TOK + lane];
        }

        // ---- Phase 2: all 4 waves stream 1024 quads (32 KB x2) ----
        const long long blkq = chunk * (TOK * 16);
#pragma unroll
        for (int it = 0; it < 4; ++it) {
            const int item = it * TPB + tid;
            const int tl = item >> 4;          // local token
            const int cd0 = (item & 15) * 4;   // offset in 64-float row
            const int cc = cd0 >> 3;
            const int d0 = cd0 & 7;            // 0 or 4
            const float* trow = &ldsT[tl * STRIDE];

            const f32x4 tcd = *(const f32x4*)(trow + cd0);   // T[c][d0..d0+3]
            const float td0 = trow[(d0 + 0) * 8 + cc];       // T[d][c]
            const float td1 = trow[(d0 + 1) * 8 + cc];
            const float td2 = trow[(d0 + 2) * 8 + cc];
            const float td3 = trow[(d0 + 3) * 8 + cc];

            f32x4 o1, o2;
            o1[0] = 0.5f * (tcd[0] - td0);  o2[0] = 0.5f * (tcd[0] + td0);
            o1[1] = 0.5f * (tcd[1] - td1);  o2[1] = 0.5f * (tcd[1] + td1);
            o1[2] = 0.5f * (tcd[2] - td2);  o2[2] = 0.5f * (tcd[2] + td2);
            o1[3] = 0.5f * (tcd[3] - td3);  o2[3] = 0.5f * (tcd[3] + td3);

            __builtin_nontemporal_store(o1, &K1[blkq + item]);
            __builtin_nontemporal_store(o2, &K2[blkq + item]);
        }
        __syncthreads();   // protect LDS before next chunk's phase 1
    }
}

extern "C" void kernel_launch(void* const* d_in, const int* in_sizes, int n_in,
                              void* d_out, int out_size, void* d_ws, size_t ws_size,
                              hipStream_t stream) {
    const float* psi = (const float*)d_in[0];
    const float* gamma = (const float*)d_in[1];
    float* out = (float*)d_out;

    const long long n_tokens = (long long)in_sizes[0] / 4;  // B*N = 524288

    spinor_bilinears_v5<<<GRID, TPB, 0, stream>>>(psi, gamma, out, n_tokens);
}